// Round 13
// baseline (184.182 us; speedup 1.0000x reference)
//
#include <hip/hip_runtime.h>
#include <stdint.h>

#define S_LEN 4096
#define HDIM  768
#define NHEAD 12
#define DHEAD 64

typedef _Float16 f16;
typedef __attribute__((ext_vector_type(8)))  _Float16 f16x8;
typedef __attribute__((ext_vector_type(4)))  _Float16 f16x4;
typedef __attribute__((ext_vector_type(4)))  float    f32x4;
typedef __attribute__((ext_vector_type(16))) float    f32x16;

typedef __attribute__((address_space(1))) void gv_t;
typedef __attribute__((address_space(3))) void lv_t;

__device__ __forceinline__ void async_copy16(const void* g, void* l) {
  __builtin_amdgcn_global_load_lds((gv_t*)g, (lv_t*)l, 16, 0, 0);
}

__device__ __forceinline__ float fast_exp2(float x) {
#if __has_builtin(__builtin_amdgcn_exp2f)
  return __builtin_amdgcn_exp2f(x);
#else
  return exp2f(x);
#endif
}

__device__ __forceinline__ int swz4(int row) { return (row ^ (row >> 2)) & 3; }

// ---------------- workspace layout (heavy reuse) ----------------
constexpr size_t OFF_META = 0;                          // int kcount
constexpr size_t OFF_RIDX = 256;                        // int[4096] inverse map p->s
constexpr size_t OFF_XB   = 65536;                      // f16 x[4096*768]
constexpr size_t SZ_XB    = (size_t)S_LEN * HDIM * 2;
constexpr size_t OFF_WQKV = OFF_XB + SZ_XB;             // f16[3*768*768]
constexpr size_t SZ_WQKV  = (size_t)3 * HDIM * HDIM * 2;
constexpr size_t OFF_WO   = OFF_WQKV + SZ_WQKV;         // f16[768*768]
constexpr size_t SZ_WO    = (size_t)HDIM * HDIM * 2;
constexpr size_t OFF_Q    = OFF_WO + SZ_WO;             // f16[12][4096][64]
constexpr size_t SZ_HD    = (size_t)NHEAD * S_LEN * DHEAD * 2;
constexpr size_t OFF_K    = OFF_Q + SZ_HD;              // f16[12][4096][64] compacted
constexpr size_t OFF_VT   = OFF_K + SZ_HD;              // f16[12][64][4096] transposed+permuted V
constexpr size_t OFF_PO   = OFF_VT + SZ_HD;             // f16[12][4096][64] normalized O

// ---------------- prep: fp32->fp16 convert + mask compaction (inverse map) ----------------
__global__ __launch_bounds__(256) void k_prep(const float* __restrict__ x,
                                              const float* __restrict__ wq,
                                              const float* __restrict__ wk,
                                              const float* __restrict__ wv,
                                              const float* __restrict__ wo,
                                              const int* __restrict__ mi,
                                              f16* __restrict__ dst,
                                              int* __restrict__ ridx,
                                              int* __restrict__ meta) {
  __shared__ int s_flag;
  __shared__ int s_cnt[256];
  const int b = blockIdx.x, tid = threadIdx.x;
  if (b < 5376) {
    int i = b * 256 + tid;                   // 1376256 float4 units
    const float* src; int off;
    if (i < 786432) { src = x; off = i; }
    else {
      int j = i - 786432;
      int w = j / 147456;
      off = j - w * 147456;
      src = (w == 0) ? wq : (w == 1) ? wk : (w == 2) ? wv : wo;
    }
    float4 v = ((const float4*)src)[off];
    f16x4 h;
    h[0] = (f16)v.x; h[1] = (f16)v.y; h[2] = (f16)v.z; h[3] = (f16)v.w;
    ((f16x4*)dst)[i] = h;
    return;
  }
  // ---- mask block ----
  if (tid == 0) s_flag = 1;
  __syncthreads();
  int bad = 0;
  #pragma unroll
  for (int k = 0; k < 4; ++k) {
    int v = mi[k * 256 + tid];
    if (v != 0 && v != 1) bad = 1;
  }
  if (bad) atomicAnd(&s_flag, 0);
  __syncthreads();
  const int isInt = s_flag;
  const unsigned char* mu8 = (const unsigned char*)mi;
  int keep[16]; int cnt = 0;
  const int s0 = tid * 16;
  #pragma unroll
  for (int k = 0; k < 16; ++k) {
    int mval = isInt ? mi[s0 + k] : (int)mu8[s0 + k];
    keep[k] = (mval == 0) ? 1 : 0;           // True => masked out (excluded)
    cnt += keep[k];
    ridx[s0 + k] = 0;                        // zero-fill inverse map (pad-safe)
  }
  s_cnt[tid] = cnt;
  __syncthreads();
  for (int off = 1; off < 256; off <<= 1) {
    int t = (tid >= off) ? s_cnt[tid - off] : 0;
    __syncthreads();
    s_cnt[tid] += t;
    __syncthreads();
  }
  int base = s_cnt[tid] - cnt;               // exclusive prefix
  #pragma unroll
  for (int k = 0; k < 16; ++k) {
    if (keep[k]) { ridx[base] = s0 + k; ++base; }
  }
  if (tid == 255) meta[0] = s_cnt[255];
}

// ---------------- fused QKV projection GEMM + V-transpose epilogue, XCD-chunked grid ----
// vs R11: 1D grid 576 with bijective chunked remap (T1): each XCD owns 4 consecutive
// m-tiles x all 18 column-tiles, so the 18 blocks sharing an A-panel (196KB of xb) hit
// the same XCD's L2 instead of round-robining across 8 XCDs (was up to ~226MB of
// L3/HBM panel re-fetch; now A is L2-resident, B streamed once and shared).
__global__ __launch_bounds__(256) void k_qkv(
    const f16* __restrict__ xb, const f16* __restrict__ wqkv,
    const float* __restrict__ bq, const float* __restrict__ bk, const float* __restrict__ bv,
    const int* __restrict__ ridx, const int* __restrict__ meta,
    f16* __restrict__ Qh, f16* __restrict__ Kc, f16* __restrict__ Vtc) {
  __shared__ __attribute__((aligned(16))) f16 lA[128 * 32];
  __shared__ __attribute__((aligned(16))) f16 lB[128 * 32];
  __shared__ __attribute__((aligned(16))) f16 lT[64 * 132];   // V-transpose bounce (16.9KB)
  const int tid = threadIdx.x;
  const int wid = tid >> 6, lane = tid & 63;
  const int hf = lane >> 5, l31 = lane & 31;
  const int wm = wid >> 1, wn = wid & 1;
  // bijective XCD-chunked decode: 576 = 8 XCDs x 72 units (4 m-tiles x 18 tn each)
  const int lid = blockIdx.x;
  const int u = (lid & 7) * 72 + (lid >> 3);
  const int tn = u % 18;
  const int m0 = (u / 18) * 128;
  const int mat = tn / 6;
  const int nb = (tn % 6) * 128;
  const int kc = meta[0];
  const int kcp = (kc + 63) & ~63;
  if (mat != 0 && m0 >= kc) return;          // fully-pad K/V tile
  const f16* wbase = wqkv + (size_t)mat * HDIM * HDIM;

  const int ar0 = tid >> 2, ar1 = 64 + (tid >> 2);
  const f16* asrc0;
  const f16* asrc1;
  if (mat == 0) {
    asrc0 = xb + (size_t)(m0 + ar0) * HDIM;
    asrc1 = xb + (size_t)(m0 + ar1) * HDIM;
  } else {
    int g0 = (m0 + ar0 < kc) ? ridx[m0 + ar0] : 0;
    int g1 = (m0 + ar1 < kc) ? ridx[m0 + ar1] : 0;
    asrc0 = xb + (size_t)g0 * HDIM;
    asrc1 = xb + (size_t)g1 * HDIM;
  }
  const int slot = tid & 3;
  const int gs0 = slot ^ swz4(ar0);
  const int gs1 = slot ^ swz4(ar1);

  f32x16 acc[2][2] = {};

  for (int k0 = 0; k0 < HDIM; k0 += 32) {
    async_copy16((const char*)(asrc0 + k0) + gs0 * 16, (char*)lA + (wid * 64) * 16);
    async_copy16((const char*)(asrc1 + k0) + gs1 * 16, (char*)lA + (256 + wid * 64) * 16);
    async_copy16((const char*)(wbase + (size_t)(nb + ar0) * HDIM + k0) + gs0 * 16,
                 (char*)lB + (wid * 64) * 16);
    async_copy16((const char*)(wbase + (size_t)(nb + ar1) * HDIM + k0) + gs1 * 16,
                 (char*)lB + (256 + wid * 64) * 16);
    __syncthreads();
    #pragma unroll
    for (int kk = 0; kk < 2; ++kk) {
      f16x8 af[2], bf[2];
      #pragma unroll
      for (int mi = 0; mi < 2; ++mi) {
        int row = wm * 64 + mi * 32 + l31;
        af[mi] = *(const f16x8*)&lA[row * 32 + (((kk * 2 + hf) ^ swz4(row)) * 8)];
      }
      #pragma unroll
      for (int ni = 0; ni < 2; ++ni) {
        int row = wn * 64 + ni * 32 + l31;
        bf[ni] = *(const f16x8*)&lB[row * 32 + (((kk * 2 + hf) ^ swz4(row)) * 8)];
      }
      #pragma unroll
      for (int mi = 0; mi < 2; ++mi)
        #pragma unroll
        for (int ni = 0; ni < 2; ++ni)
          acc[mi][ni] = __builtin_amdgcn_mfma_f32_32x32x16_f16(af[mi], bf[ni], acc[mi][ni], 0, 0, 0);
    }
    __syncthreads();
  }

  if (mat == 2) {
    // ---- fused V epilogue: transpose+permute to Vtc[h][d][p] via lT ----
    const float* bias = bv;
    #pragma unroll
    for (int pass = 0; pass < 2; ++pass) {     // pass == head_local == wn
      __syncthreads();
      if (wn == pass) {
        #pragma unroll
        for (int ni = 0; ni < 2; ++ni) {
          const int n = nb + wn * 64 + ni * 32 + l31;
          const float bn = bias[n];
          const int dloc = ni * 32 + l31;
          #pragma unroll
          for (int mi = 0; mi < 2; ++mi) {
            #pragma unroll
            for (int rg = 0; rg < 4; ++rg) {   // 4 consecutive s per group
              const int sbase = wm * 64 + mi * 32 + 8 * rg + 4 * hf;
              f16x4 v4;
              #pragma unroll
              for (int j = 0; j < 4; ++j) {
                const int s = m0 + sbase + j;
                v4[j] = (s < kc) ? (f16)(acc[mi][ni][rg * 4 + j] + bn) : (f16)0.f;
              }
              *(f16x4*)&lT[dloc * 132 + sbase] = v4;
            }
          }
        }
      }
      __syncthreads();
      const int headg = (nb >> 6) + pass;
      // 64 d x 16 chunks of 8 keys, k_vt's within-16 bit-2<->3 swap:
      for (int u2 = tid; u2 < 1024; u2 += 256) {
        const int d = u2 >> 4, p8 = u2 & 15;
        const int base16 = (p8 >> 1) * 16, half = p8 & 1;
        f16x4 lo = *(const f16x4*)&lT[d * 132 + base16 + half * 4];
        f16x4 hi = *(const f16x4*)&lT[d * 132 + base16 + 8 + half * 4];
        f16x8 o;
        o[0] = lo[0]; o[1] = lo[1]; o[2] = lo[2]; o[3] = lo[3];
        o[4] = hi[0]; o[5] = hi[1]; o[6] = hi[2]; o[7] = hi[3];
        *(f16x8*)&Vtc[((size_t)headg * DHEAD + d) * S_LEN + m0 + p8 * 8] = o;
      }
    }
    return;
  }

  const float* bias = (mat == 0) ? bq : bk;
  const float qscale = 0.125f * 1.44269504088896341f;  // 1/sqrt(64) * log2(e)
  #pragma unroll
  for (int mi = 0; mi < 2; ++mi) {
    #pragma unroll
    for (int ni = 0; ni < 2; ++ni) {
      int n = nb + wn * 64 + ni * 32 + l31;
      int head = n >> 6, d = n & 63;
      float b = bias[n];
      #pragma unroll
      for (int reg = 0; reg < 16; ++reg) {
        int s = m0 + wm * 64 + mi * 32 + (reg & 3) + 8 * (reg >> 2) + 4 * hf;
        float val = acc[mi][ni][reg] + b;
        if (mat == 0) {
          Qh[((size_t)head * S_LEN + s) * DHEAD + d] = (f16)(val * qscale);
        } else if (s < kc) {
          Kc[((size_t)head * S_LEN + s) * DHEAD + d] = (f16)val;
        } else if (s < kcp) {
          Kc[((size_t)head * S_LEN + s) * DHEAD + d] = (f16)0.f;   // K pad rows -> P=1
        }
      }
    }
  }
}

// ---------------- flash attention: single-split + cross-phase ILP (R11, best measured) ---
__global__ __launch_bounds__(128, 2) void k_attn(
    const f16* __restrict__ Qh, const f16* __restrict__ Kc, const f16* __restrict__ Vtc,
    const int* __restrict__ meta, f16* __restrict__ PO) {
  __shared__ __attribute__((aligned(16))) f16 lK[2][64 * 64];   // [buf][key][d] swizzled
  __shared__ __attribute__((aligned(16))) f16 lV[2][64 * 64];   // [buf][d][rho] swizzled
  __shared__ float lil[64];                                     // per-query 1/l
  const int tid = threadIdx.x;            // 0..127
  const int wid = tid >> 6, lane = tid & 63;
  const int hf = lane >> 5, l31 = lane & 31, r7 = l31 & 7;

  // XCD head-clustering: 768 blocks, 96 contiguous work units per XCD.
  const int lid = blockIdx.x;
  const int w = ((lid & 7) * 96) + (lid >> 3);
  const int head = w >> 6;
  const int q0 = (w & 63) * 64 + wid * 32;   // wave's 32-query base

  const int kc = meta[0];
  const int nkt = (kc + 63) >> 6;

  const f16* Qp = Qh + ((size_t)head * S_LEN + q0 + l31) * DHEAD;
  f16x8 qf[4];
  #pragma unroll
  for (int dc = 0; dc < 4; ++dc) qf[dc] = *(const f16x8*)(Qp + dc * 16 + hf * 8);

  f32x16 accO[2] = {};
  float ls0 = 0.f, ls1 = 0.f, ls2 = 0.f, ls3 = 0.f;

  const char* kbase = (const char*)(Kc + (size_t)head * S_LEN * DHEAD);
  const char* vbase = (const char*)(Vtc + (size_t)head * DHEAD * S_LEN);

  const int crow = tid >> 3, cslot = tid & 7;
  const int gsc = cslot ^ (crow & 7);

  auto stage = [&](int t, int buf) {
    const int j0 = t * 64;
    #pragma unroll
    for (int it = 0; it < 4; ++it) {
      const int row = it * 16 + crow;
      async_copy16(kbase + (size_t)(j0 + row) * 128 + gsc * 16,
                   (char*)&lK[buf][0] + (it * 128 + wid * 64) * 16);
      async_copy16(vbase + (size_t)row * (S_LEN * 2) + (size_t)j0 * 2 + gsc * 16,
                   (char*)&lV[buf][0] + (it * 128 + wid * 64) * 16);
    }
  };

  int cur = 0;
  stage(0, 0);
  __syncthreads();

  for (int t = 0; t < nkt; ++t) {
    const bool more = (t + 1 < nkt);
    if (more) stage(t + 1, cur ^ 1);

    // ---- QK both halves: 2 independent MFMA chains issued back-to-back ----
    f16x8 af0[4], af1[4];
    #pragma unroll
    for (int dc = 0; dc < 4; ++dc) {
      af0[dc] = *(const f16x8*)&lK[cur][l31 * 64 + ((((dc << 1) | hf) ^ r7) * 8)];
      af1[dc] = *(const f16x8*)&lK[cur][(32 + l31) * 64 + ((((dc << 1) | hf) ^ r7) * 8)];
    }
    f32x16 sA = {}, sB = {};
    #pragma unroll
    for (int dc = 0; dc < 4; ++dc) {
      sA = __builtin_amdgcn_mfma_f32_32x32x16_f16(af0[dc], qf[dc], sA, 0, 0, 0);
      sB = __builtin_amdgcn_mfma_f32_32x32x16_f16(af1[dc], qf[dc], sB, 0, 0, 0);
    }

    // ---- exp A (sA ready: 8 MFMAs issued since its chain ended) ----
    f16x8 pfA[2];
    #pragma unroll
    for (int u = 0; u < 16; ++u) {
      sA[u] = fast_exp2(sA[u]);
      if (u & 1) ls1 += sA[u]; else ls0 += sA[u];
    }
    #pragma unroll
    for (int cc = 0; cc < 2; ++cc)
      #pragma unroll
      for (int u = 0; u < 8; ++u) pfA[cc][u] = (f16)sA[8 * cc + u];

    // ---- PV A issue (c2 = 0,1); exp B runs in its MFMA shadow ----
    #pragma unroll
    for (int cc = 0; cc < 2; ++cc) {
      #pragma unroll
      for (int dh = 0; dh < 2; ++dh) {
        const int vrow = dh * 32 + l31;
        f16x8 vf = *(const f16x8*)&lV[cur][vrow * 64 + ((((cc << 1) | hf) ^ r7) * 8)];
        accO[dh] = __builtin_amdgcn_mfma_f32_32x32x16_f16(pfA[cc], vf, accO[dh], 0, 0, 0);
      }
    }

    f16x8 pfB[2];
    #pragma unroll
    for (int u = 0; u < 16; ++u) {
      sB[u] = fast_exp2(sB[u]);
      if (u & 1) ls3 += sB[u]; else ls2 += sB[u];
    }
    #pragma unroll
    for (int cc = 0; cc < 2; ++cc)
      #pragma unroll
      for (int u = 0; u < 8; ++u) pfB[cc][u] = (f16)sB[8 * cc + u];

    // ---- PV B (c2 = 2,3) ----
    #pragma unroll
    for (int cc = 0; cc < 2; ++cc) {
      #pragma unroll
      for (int dh = 0; dh < 2; ++dh) {
        const int vrow = dh * 32 + l31;
        f16x8 vf = *(const f16x8*)&lV[cur][vrow * 64 + (((((2 + cc) << 1) | hf) ^ r7) * 8)];
        accO[dh] = __builtin_amdgcn_mfma_f32_32x32x16_f16(pfB[cc], vf, accO[dh], 0, 0, 0);
      }
    }

    if (more) {
      __syncthreads();
      cur ^= 1;
    }
  }

  float lsum = (ls0 + ls1) + (ls2 + ls3);
  lsum += __shfl_xor(lsum, 32);              // fold hf halves
  lsum -= (float)(nkt * 64 - kc);            // pad keys (zero K rows) contribute exp=1
  if (hf == 0) lil[wid * 32 + l31] = 1.0f / lsum;
  __syncthreads();                           // publishes lil; all lK/lV reads done

  // normalized, coalesced PO store via LDS bounce (reuse dead lK; 4KB per wave)
  f16* ost = (f16*)lK + wid * 2048;
  #pragma unroll
  for (int dh = 0; dh < 2; ++dh)
    #pragma unroll
    for (int reg = 0; reg < 16; ++reg) {
      int row = (reg & 3) + 8 * (reg >> 2) + 4 * hf;
      ost[row * 64 + dh * 32 + l31] = (f16)(accO[dh][reg] * lil[wid * 32 + row]);
    }
  #pragma unroll
  for (int p = 0; p < 4; ++p) {
    int row = p * 8 + (lane >> 3), sl = lane & 7;
    f16x8 v = *(const f16x8*)&ost[row * 64 + sl * 8];
    *(f16x8*)&PO[((size_t)head * S_LEN + q0 + row) * DHEAD + sl * 8] = v;
  }
}

// ---------------- output projection GEMM: single normalized PO, all-async staging --------
__global__ __launch_bounds__(256) void k_out(
    const f16* __restrict__ PO, const f16* __restrict__ wo,
    const float* __restrict__ bo, float* __restrict__ out) {
  __shared__ __attribute__((aligned(16))) f16 lA[128 * 64];   // 16KB
  __shared__ __attribute__((aligned(16))) f16 lB[64 * 64];    // 8KB
  const int tid = threadIdx.x;
  const int wid = tid >> 6, lane = tid & 63;
  const int hf = lane >> 5, l31 = lane & 31;
  const int wm = wid >> 1, wn = wid & 1;     // 2x2 waves of 64m x 32n
  const int lid = blockIdx.x;
  const int w = ((lid & 7) * 48) + (lid >> 3);   // XCD-grouped: 48 units/XCD share m-tiles
  const int nb = (w % 12) * 64;
  const int m0 = (w / 12) * 128;

  f32x16 acc[2] = {};   // [mi]

  for (int head = 0; head < NHEAD; ++head) {   // BK=64 == one head per step
    // A: PO rows (already normalized f16) via async; 1024 chunks
    #pragma unroll
    for (int it = 0; it < 4; ++it) {
      int c = it * 256 + tid;
      int row = c >> 3, slot = c & 7;
      int gs = slot ^ (row & 7);
      async_copy16((const char*)(PO + ((size_t)head * S_LEN + m0 + row) * DHEAD) + gs * 16,
                   (char*)lA + (it * 256 + wid * 64) * 16);
    }
    // B: wo rows (output cols) nb..nb+63, k-range head*64..+64; 512 chunks
    #pragma unroll
    for (int it = 0; it < 2; ++it) {
      int c = it * 256 + tid;
      int row = c >> 3, slot = c & 7;
      int gs = slot ^ (row & 7);
      async_copy16((const char*)(wo + (size_t)(nb + row) * HDIM + head * 64) + gs * 16,
                   (char*)lB + (it * 256 + wid * 64) * 16);
    }
    __syncthreads();
    #pragma unroll
    for (int kk = 0; kk < 4; ++kk) {
      f16x8 af[2], bf;
      #pragma unroll
      for (int mi = 0; mi < 2; ++mi) {
        int row = wm * 64 + mi * 32 + l31;
        af[mi] = *(const f16x8*)&lA[row * 64 + ((((kk << 1) | hf) ^ (row & 7)) * 8)];
      }
      int rb = wn * 32 + l31;
      bf = *(const f16x8*)&lB[rb * 64 + ((((kk << 1) | hf) ^ (rb & 7)) * 8)];
      #pragma unroll
      for (int mi = 0; mi < 2; ++mi)
        acc[mi] = __builtin_amdgcn_mfma_f32_32x32x16_f16(af[mi], bf, acc[mi], 0, 0, 0);
    }
    __syncthreads();
  }

  const int n = nb + wn * 32 + l31;
  const float b = bo[n];
  #pragma unroll
  for (int mi = 0; mi < 2; ++mi) {
    #pragma unroll
    for (int reg = 0; reg < 16; ++reg) {
      int s = m0 + wm * 64 + mi * 32 + (reg & 3) + 8 * (reg >> 2) + 4 * hf;
      out[(size_t)s * HDIM + n] = acc[mi][reg] + b;
    }
  }
}

extern "C" void kernel_launch(void* const* d_in, const int* in_sizes, int n_in,
                              void* d_out, int out_size, void* d_ws, size_t ws_size,
                              hipStream_t stream) {
  const float* x  = (const float*)d_in[0];
  const float* Wq = (const float*)d_in[1];
  const float* bq = (const float*)d_in[2];
  const float* Wk = (const float*)d_in[3];
  const float* bk = (const float*)d_in[4];
  const float* Wv = (const float*)d_in[5];
  const float* bv = (const float*)d_in[6];
  const float* Wo = (const float*)d_in[7];
  const float* bo = (const float*)d_in[8];
  const int*   mask = (const int*)d_in[9];
  float* out = (float*)d_out;

  char* ws = (char*)d_ws;
  int* meta  = (int*)(ws + OFF_META);
  int* ridx  = (int*)(ws + OFF_RIDX);
  f16* xb    = (f16*)(ws + OFF_XB);
  f16* wqkv  = (f16*)(ws + OFF_WQKV);
  f16* wob   = (f16*)(ws + OFF_WO);
  f16* Qh    = (f16*)(ws + OFF_Q);
  f16* Kc    = (f16*)(ws + OFF_K);
  f16* Vtc   = (f16*)(ws + OFF_VT);
  f16* PO    = (f16*)(ws + OFF_PO);

  k_prep<<<dim3(5377), 256, 0, stream>>>(x, Wq, Wk, Wv, Wo, mask, xb, ridx, meta);
  k_qkv<<<dim3(576), 256, 0, stream>>>(xb, wqkv, bq, bk, bv, ridx, meta, Qh, Kc, Vtc);
  k_attn<<<dim3(768), 128, 0, stream>>>(Qh, Kc, Vtc, meta, PO);
  k_out<<<dim3(384), 256, 0, stream>>>(PO, wob, bo, out);
}

// Round 14
// 168.025 us; speedup vs baseline: 1.0962x; 1.0962x over previous
//
#include <hip/hip_runtime.h>
#include <stdint.h>

#define S_LEN 4096
#define HDIM  768
#define NHEAD 12
#define DHEAD 64

typedef _Float16 f16;
typedef __attribute__((ext_vector_type(8)))  _Float16 f16x8;
typedef __attribute__((ext_vector_type(4)))  _Float16 f16x4;
typedef __attribute__((ext_vector_type(4)))  float    f32x4;
typedef __attribute__((ext_vector_type(16))) float    f32x16;

typedef __attribute__((address_space(1))) void gv_t;
typedef __attribute__((address_space(3))) void lv_t;

__device__ __forceinline__ void async_copy16(const void* g, void* l) {
  __builtin_amdgcn_global_load_lds((gv_t*)g, (lv_t*)l, 16, 0, 0);
}

__device__ __forceinline__ float fast_exp2(float x) {
#if __has_builtin(__builtin_amdgcn_exp2f)
  return __builtin_amdgcn_exp2f(x);
#else
  return exp2f(x);
#endif
}

__device__ __forceinline__ int swz4(int row) { return (row ^ (row >> 2)) & 3; }

// ---------------- workspace layout (heavy reuse) ----------------
constexpr size_t OFF_META = 0;                          // int kcount
constexpr size_t OFF_RIDX = 256;                        // int[4096] inverse map p->s
constexpr size_t OFF_XB   = 65536;                      // f16 x[4096*768]
constexpr size_t SZ_XB    = (size_t)S_LEN * HDIM * 2;
constexpr size_t OFF_WQKV = OFF_XB + SZ_XB;             // f16[3*768*768]
constexpr size_t SZ_WQKV  = (size_t)3 * HDIM * HDIM * 2;
constexpr size_t OFF_WO   = OFF_WQKV + SZ_WQKV;         // f16[768*768]
constexpr size_t SZ_WO    = (size_t)HDIM * HDIM * 2;
constexpr size_t OFF_Q    = OFF_WO + SZ_WO;             // f16[12][4096][64]
constexpr size_t SZ_HD    = (size_t)NHEAD * S_LEN * DHEAD * 2;
constexpr size_t OFF_K    = OFF_Q + SZ_HD;              // f16[12][4096][64] compacted
constexpr size_t OFF_VT   = OFF_K + SZ_HD;              // f16[12][64][4096] transposed+permuted V
constexpr size_t OFF_PO   = OFF_VT + SZ_HD;             // f16[12][4096][64] normalized O

// ---------------- prep: fp32->fp16 convert + mask compaction (inverse map) ----------------
__global__ __launch_bounds__(256) void k_prep(const float* __restrict__ x,
                                              const float* __restrict__ wq,
                                              const float* __restrict__ wk,
                                              const float* __restrict__ wv,
                                              const float* __restrict__ wo,
                                              const int* __restrict__ mi,
                                              f16* __restrict__ dst,
                                              int* __restrict__ ridx,
                                              int* __restrict__ meta) {
  __shared__ int s_flag;
  __shared__ int s_cnt[256];
  const int b = blockIdx.x, tid = threadIdx.x;
  if (b < 5376) {
    int i = b * 256 + tid;                   // 1376256 float4 units
    const float* src; int off;
    if (i < 786432) { src = x; off = i; }
    else {
      int j = i - 786432;
      int w = j / 147456;
      off = j - w * 147456;
      src = (w == 0) ? wq : (w == 1) ? wk : (w == 2) ? wv : wo;
    }
    float4 v = ((const float4*)src)[off];
    f16x4 h;
    h[0] = (f16)v.x; h[1] = (f16)v.y; h[2] = (f16)v.z; h[3] = (f16)v.w;
    ((f16x4*)dst)[i] = h;
    return;
  }
  // ---- mask block ----
  if (tid == 0) s_flag = 1;
  __syncthreads();
  int bad = 0;
  #pragma unroll
  for (int k = 0; k < 4; ++k) {
    int v = mi[k * 256 + tid];
    if (v != 0 && v != 1) bad = 1;
  }
  if (bad) atomicAnd(&s_flag, 0);
  __syncthreads();
  const int isInt = s_flag;
  const unsigned char* mu8 = (const unsigned char*)mi;
  int keep[16]; int cnt = 0;
  const int s0 = tid * 16;
  #pragma unroll
  for (int k = 0; k < 16; ++k) {
    int mval = isInt ? mi[s0 + k] : (int)mu8[s0 + k];
    keep[k] = (mval == 0) ? 1 : 0;           // True => masked out (excluded)
    cnt += keep[k];
    ridx[s0 + k] = 0;                        // zero-fill inverse map (pad-safe)
  }
  s_cnt[tid] = cnt;
  __syncthreads();
  for (int off = 1; off < 256; off <<= 1) {
    int t = (tid >= off) ? s_cnt[tid - off] : 0;
    __syncthreads();
    s_cnt[tid] += t;
    __syncthreads();
  }
  int base = s_cnt[tid] - cnt;               // exclusive prefix
  #pragma unroll
  for (int k = 0; k < 16; ++k) {
    if (keep[k]) { ridx[base] = s0 + k; ++base; }
  }
  if (tid == 255) meta[0] = s_cnt[255];
}

// ---------------- fused QKV projection GEMM + V-transpose epilogue, BK=64 ---------------
// vs R11 (grid (18,32) restored after R13's imbalance regression): BK 32->64 halves the
// stage->vmcnt(0)->barrier drain count (24->12 steps) and doubles MFMA per drain (16->32
// 32x32x16 per step per wave). R13's +15us proved k_qkv is ~25-40us, far above its
// ~13us roofline, and it was the last kernel still on the 24-drain structure. LDS
// 16+16+16.9=48.9KB -> 3 blocks/CU (grid needs 2.25, still fully resident).
__global__ __launch_bounds__(256) void k_qkv(
    const f16* __restrict__ xb, const f16* __restrict__ wqkv,
    const float* __restrict__ bq, const float* __restrict__ bk, const float* __restrict__ bv,
    const int* __restrict__ ridx, const int* __restrict__ meta,
    f16* __restrict__ Qh, f16* __restrict__ Kc, f16* __restrict__ Vtc) {
  __shared__ __attribute__((aligned(16))) f16 lA[128 * 64];   // 16KB
  __shared__ __attribute__((aligned(16))) f16 lB[128 * 64];   // 16KB
  __shared__ __attribute__((aligned(16))) f16 lT[64 * 132];   // V-transpose bounce (16.9KB)
  const int tid = threadIdx.x;
  const int wid = tid >> 6, lane = tid & 63;
  const int hf = lane >> 5, l31 = lane & 31;
  const int wm = wid >> 1, wn = wid & 1;
  const int tn = blockIdx.x;
  const int m0 = blockIdx.y * 128;
  const int mat = tn / 6;
  const int nb = (tn % 6) * 128;
  const int kc = meta[0];
  const int kcp = (kc + 63) & ~63;
  if (mat != 0 && m0 >= kc) return;          // fully-pad K/V tile
  const f16* wbase = wqkv + (size_t)mat * HDIM * HDIM;

  // 4 A-rows + 4 B-rows per thread: chunk c = it*256+tid -> row = it*32+(tid>>3)
  const int r8 = tid >> 3;                   // 0..31
  const int slot = tid & 7;
  const int gs = slot ^ (r8 & 7);            // it*32 doesn't change row&7
  const f16* asrc[4];
  #pragma unroll
  for (int it = 0; it < 4; ++it) {
    int r = it * 32 + r8;
    if (mat == 0) {
      asrc[it] = xb + (size_t)(m0 + r) * HDIM;
    } else {
      int g = (m0 + r < kc) ? ridx[m0 + r] : 0;
      asrc[it] = xb + (size_t)g * HDIM;
    }
  }

  f32x16 acc[2][2] = {};

  for (int k0 = 0; k0 < HDIM; k0 += 64) {
    #pragma unroll
    for (int it = 0; it < 4; ++it) {
      int r = it * 32 + r8;
      async_copy16((const char*)(asrc[it] + k0) + gs * 16,
                   (char*)lA + (it * 256 + wid * 64) * 16);
      async_copy16((const char*)(wbase + (size_t)(nb + r) * HDIM + k0) + gs * 16,
                   (char*)lB + (it * 256 + wid * 64) * 16);
    }
    __syncthreads();
    #pragma unroll
    for (int kk = 0; kk < 4; ++kk) {
      f16x8 af[2], bf[2];
      #pragma unroll
      for (int mi = 0; mi < 2; ++mi) {
        int row = wm * 64 + mi * 32 + l31;
        af[mi] = *(const f16x8*)&lA[row * 64 + ((((kk << 1) | hf) ^ (row & 7)) * 8)];
      }
      #pragma unroll
      for (int ni = 0; ni < 2; ++ni) {
        int row = wn * 64 + ni * 32 + l31;
        bf[ni] = *(const f16x8*)&lB[row * 64 + ((((kk << 1) | hf) ^ (row & 7)) * 8)];
      }
      #pragma unroll
      for (int mi = 0; mi < 2; ++mi)
        #pragma unroll
        for (int ni = 0; ni < 2; ++ni)
          acc[mi][ni] = __builtin_amdgcn_mfma_f32_32x32x16_f16(af[mi], bf[ni], acc[mi][ni], 0, 0, 0);
    }
    __syncthreads();
  }

  if (mat == 2) {
    // ---- fused V epilogue: transpose+permute to Vtc[h][d][p] via lT ----
    const float* bias = bv;
    #pragma unroll
    for (int pass = 0; pass < 2; ++pass) {     // pass == head_local == wn
      __syncthreads();
      if (wn == pass) {
        #pragma unroll
        for (int ni = 0; ni < 2; ++ni) {
          const int n = nb + wn * 64 + ni * 32 + l31;
          const float bn = bias[n];
          const int dloc = ni * 32 + l31;
          #pragma unroll
          for (int mi = 0; mi < 2; ++mi) {
            #pragma unroll
            for (int rg = 0; rg < 4; ++rg) {   // 4 consecutive s per group
              const int sbase = wm * 64 + mi * 32 + 8 * rg + 4 * hf;
              f16x4 v4;
              #pragma unroll
              for (int j = 0; j < 4; ++j) {
                const int s = m0 + sbase + j;
                v4[j] = (s < kc) ? (f16)(acc[mi][ni][rg * 4 + j] + bn) : (f16)0.f;
              }
              *(f16x4*)&lT[dloc * 132 + sbase] = v4;
            }
          }
        }
      }
      __syncthreads();
      const int headg = (nb >> 6) + pass;
      // 64 d x 16 chunks of 8 keys, k_vt's within-16 bit-2<->3 swap:
      for (int u2 = tid; u2 < 1024; u2 += 256) {
        const int d = u2 >> 4, p8 = u2 & 15;
        const int base16 = (p8 >> 1) * 16, half = p8 & 1;
        f16x4 lo = *(const f16x4*)&lT[d * 132 + base16 + half * 4];
        f16x4 hi = *(const f16x4*)&lT[d * 132 + base16 + 8 + half * 4];
        f16x8 o;
        o[0] = lo[0]; o[1] = lo[1]; o[2] = lo[2]; o[3] = lo[3];
        o[4] = hi[0]; o[5] = hi[1]; o[6] = hi[2]; o[7] = hi[3];
        *(f16x8*)&Vtc[((size_t)headg * DHEAD + d) * S_LEN + m0 + p8 * 8] = o;
      }
    }
    return;
  }

  const float* bias = (mat == 0) ? bq : bk;
  const float qscale = 0.125f * 1.44269504088896341f;  // 1/sqrt(64) * log2(e)
  #pragma unroll
  for (int mi = 0; mi < 2; ++mi) {
    #pragma unroll
    for (int ni = 0; ni < 2; ++ni) {
      int n = nb + wn * 64 + ni * 32 + l31;
      int head = n >> 6, d = n & 63;
      float b = bias[n];
      #pragma unroll
      for (int reg = 0; reg < 16; ++reg) {
        int s = m0 + wm * 64 + mi * 32 + (reg & 3) + 8 * (reg >> 2) + 4 * hf;
        float val = acc[mi][ni][reg] + b;
        if (mat == 0) {
          Qh[((size_t)head * S_LEN + s) * DHEAD + d] = (f16)(val * qscale);
        } else if (s < kc) {
          Kc[((size_t)head * S_LEN + s) * DHEAD + d] = (f16)val;
        } else if (s < kcp) {
          Kc[((size_t)head * S_LEN + s) * DHEAD + d] = (f16)0.f;   // K pad rows -> P=1
        }
      }
    }
  }
}

// ---------------- flash attention: single-split + cross-phase ILP (R11, best measured) ---
__global__ __launch_bounds__(128, 2) void k_attn(
    const f16* __restrict__ Qh, const f16* __restrict__ Kc, const f16* __restrict__ Vtc,
    const int* __restrict__ meta, f16* __restrict__ PO) {
  __shared__ __attribute__((aligned(16))) f16 lK[2][64 * 64];   // [buf][key][d] swizzled
  __shared__ __attribute__((aligned(16))) f16 lV[2][64 * 64];   // [buf][d][rho] swizzled
  __shared__ float lil[64];                                     // per-query 1/l
  const int tid = threadIdx.x;            // 0..127
  const int wid = tid >> 6, lane = tid & 63;
  const int hf = lane >> 5, l31 = lane & 31, r7 = l31 & 7;

  // XCD head-clustering: 768 blocks, 96 contiguous work units per XCD.
  const int lid = blockIdx.x;
  const int w = ((lid & 7) * 96) + (lid >> 3);
  const int head = w >> 6;
  const int q0 = (w & 63) * 64 + wid * 32;   // wave's 32-query base

  const int kc = meta[0];
  const int nkt = (kc + 63) >> 6;

  const f16* Qp = Qh + ((size_t)head * S_LEN + q0 + l31) * DHEAD;
  f16x8 qf[4];
  #pragma unroll
  for (int dc = 0; dc < 4; ++dc) qf[dc] = *(const f16x8*)(Qp + dc * 16 + hf * 8);

  f32x16 accO[2] = {};
  float ls0 = 0.f, ls1 = 0.f, ls2 = 0.f, ls3 = 0.f;

  const char* kbase = (const char*)(Kc + (size_t)head * S_LEN * DHEAD);
  const char* vbase = (const char*)(Vtc + (size_t)head * DHEAD * S_LEN);

  const int crow = tid >> 3, cslot = tid & 7;
  const int gsc = cslot ^ (crow & 7);

  auto stage = [&](int t, int buf) {
    const int j0 = t * 64;
    #pragma unroll
    for (int it = 0; it < 4; ++it) {
      const int row = it * 16 + crow;
      async_copy16(kbase + (size_t)(j0 + row) * 128 + gsc * 16,
                   (char*)&lK[buf][0] + (it * 128 + wid * 64) * 16);
      async_copy16(vbase + (size_t)row * (S_LEN * 2) + (size_t)j0 * 2 + gsc * 16,
                   (char*)&lV[buf][0] + (it * 128 + wid * 64) * 16);
    }
  };

  int cur = 0;
  stage(0, 0);
  __syncthreads();

  for (int t = 0; t < nkt; ++t) {
    const bool more = (t + 1 < nkt);
    if (more) stage(t + 1, cur ^ 1);

    // ---- QK both halves: 2 independent MFMA chains issued back-to-back ----
    f16x8 af0[4], af1[4];
    #pragma unroll
    for (int dc = 0; dc < 4; ++dc) {
      af0[dc] = *(const f16x8*)&lK[cur][l31 * 64 + ((((dc << 1) | hf) ^ r7) * 8)];
      af1[dc] = *(const f16x8*)&lK[cur][(32 + l31) * 64 + ((((dc << 1) | hf) ^ r7) * 8)];
    }
    f32x16 sA = {}, sB = {};
    #pragma unroll
    for (int dc = 0; dc < 4; ++dc) {
      sA = __builtin_amdgcn_mfma_f32_32x32x16_f16(af0[dc], qf[dc], sA, 0, 0, 0);
      sB = __builtin_amdgcn_mfma_f32_32x32x16_f16(af1[dc], qf[dc], sB, 0, 0, 0);
    }

    // ---- exp A (sA ready: 8 MFMAs issued since its chain ended) ----
    f16x8 pfA[2];
    #pragma unroll
    for (int u = 0; u < 16; ++u) {
      sA[u] = fast_exp2(sA[u]);
      if (u & 1) ls1 += sA[u]; else ls0 += sA[u];
    }
    #pragma unroll
    for (int cc = 0; cc < 2; ++cc)
      #pragma unroll
      for (int u = 0; u < 8; ++u) pfA[cc][u] = (f16)sA[8 * cc + u];

    // ---- PV A issue (c2 = 0,1); exp B runs in its MFMA shadow ----
    #pragma unroll
    for (int cc = 0; cc < 2; ++cc) {
      #pragma unroll
      for (int dh = 0; dh < 2; ++dh) {
        const int vrow = dh * 32 + l31;
        f16x8 vf = *(const f16x8*)&lV[cur][vrow * 64 + ((((cc << 1) | hf) ^ r7) * 8)];
        accO[dh] = __builtin_amdgcn_mfma_f32_32x32x16_f16(pfA[cc], vf, accO[dh], 0, 0, 0);
      }
    }

    f16x8 pfB[2];
    #pragma unroll
    for (int u = 0; u < 16; ++u) {
      sB[u] = fast_exp2(sB[u]);
      if (u & 1) ls3 += sB[u]; else ls2 += sB[u];
    }
    #pragma unroll
    for (int cc = 0; cc < 2; ++cc)
      #pragma unroll
      for (int u = 0; u < 8; ++u) pfB[cc][u] = (f16)sB[8 * cc + u];

    // ---- PV B (c2 = 2,3) ----
    #pragma unroll
    for (int cc = 0; cc < 2; ++cc) {
      #pragma unroll
      for (int dh = 0; dh < 2; ++dh) {
        const int vrow = dh * 32 + l31;
        f16x8 vf = *(const f16x8*)&lV[cur][vrow * 64 + (((((2 + cc) << 1) | hf) ^ r7) * 8)];
        accO[dh] = __builtin_amdgcn_mfma_f32_32x32x16_f16(pfB[cc], vf, accO[dh], 0, 0, 0);
      }
    }

    if (more) {
      __syncthreads();
      cur ^= 1;
    }
  }

  float lsum = (ls0 + ls1) + (ls2 + ls3);
  lsum += __shfl_xor(lsum, 32);              // fold hf halves
  lsum -= (float)(nkt * 64 - kc);            // pad keys (zero K rows) contribute exp=1
  if (hf == 0) lil[wid * 32 + l31] = 1.0f / lsum;
  __syncthreads();                           // publishes lil; all lK/lV reads done

  // normalized, coalesced PO store via LDS bounce (reuse dead lK; 4KB per wave)
  f16* ost = (f16*)lK + wid * 2048;
  #pragma unroll
  for (int dh = 0; dh < 2; ++dh)
    #pragma unroll
    for (int reg = 0; reg < 16; ++reg) {
      int row = (reg & 3) + 8 * (reg >> 2) + 4 * hf;
      ost[row * 64 + dh * 32 + l31] = (f16)(accO[dh][reg] * lil[wid * 32 + row]);
    }
  #pragma unroll
  for (int p = 0; p < 4; ++p) {
    int row = p * 8 + (lane >> 3), sl = lane & 7;
    f16x8 v = *(const f16x8*)&ost[row * 64 + sl * 8];
    *(f16x8*)&PO[((size_t)head * S_LEN + q0 + row) * DHEAD + sl * 8] = v;
  }
}

// ---------------- output projection GEMM: single normalized PO, all-async staging --------
__global__ __launch_bounds__(256) void k_out(
    const f16* __restrict__ PO, const f16* __restrict__ wo,
    const float* __restrict__ bo, float* __restrict__ out) {
  __shared__ __attribute__((aligned(16))) f16 lA[128 * 64];   // 16KB
  __shared__ __attribute__((aligned(16))) f16 lB[64 * 64];    // 8KB
  const int tid = threadIdx.x;
  const int wid = tid >> 6, lane = tid & 63;
  const int hf = lane >> 5, l31 = lane & 31;
  const int wm = wid >> 1, wn = wid & 1;     // 2x2 waves of 64m x 32n
  const int lid = blockIdx.x;
  const int w = ((lid & 7) * 48) + (lid >> 3);   // XCD-grouped: 48 units/XCD share m-tiles
  const int nb = (w % 12) * 64;
  const int m0 = (w / 12) * 128;

  f32x16 acc[2] = {};   // [mi]

  for (int head = 0; head < NHEAD; ++head) {   // BK=64 == one head per step
    // A: PO rows (already normalized f16) via async; 1024 chunks
    #pragma unroll
    for (int it = 0; it < 4; ++it) {
      int c = it * 256 + tid;
      int row = c >> 3, slot = c & 7;
      int gs = slot ^ (row & 7);
      async_copy16((const char*)(PO + ((size_t)head * S_LEN + m0 + row) * DHEAD) + gs * 16,
                   (char*)lA + (it * 256 + wid * 64) * 16);
    }
    // B: wo rows (output cols) nb..nb+63, k-range head*64..+64; 512 chunks
    #pragma unroll
    for (int it = 0; it < 2; ++it) {
      int c = it * 256 + tid;
      int row = c >> 3, slot = c & 7;
      int gs = slot ^ (row & 7);
      async_copy16((const char*)(wo + (size_t)(nb + row) * HDIM + head * 64) + gs * 16,
                   (char*)lB + (it * 256 + wid * 64) * 16);
    }
    __syncthreads();
    #pragma unroll
    for (int kk = 0; kk < 4; ++kk) {
      f16x8 af[2], bf;
      #pragma unroll
      for (int mi = 0; mi < 2; ++mi) {
        int row = wm * 64 + mi * 32 + l31;
        af[mi] = *(const f16x8*)&lA[row * 64 + ((((kk << 1) | hf) ^ (row & 7)) * 8)];
      }
      int rb = wn * 32 + l31;
      bf = *(const f16x8*)&lB[rb * 64 + ((((kk << 1) | hf) ^ (rb & 7)) * 8)];
      #pragma unroll
      for (int mi = 0; mi < 2; ++mi)
        acc[mi] = __builtin_amdgcn_mfma_f32_32x32x16_f16(af[mi], bf, acc[mi], 0, 0, 0);
    }
    __syncthreads();
  }

  const int n = nb + wn * 32 + l31;
  const float b = bo[n];
  #pragma unroll
  for (int mi = 0; mi < 2; ++mi) {
    #pragma unroll
    for (int reg = 0; reg < 16; ++reg) {
      int s = m0 + wm * 64 + mi * 32 + (reg & 3) + 8 * (reg >> 2) + 4 * hf;
      out[(size_t)s * HDIM + n] = acc[mi][reg] + b;
    }
  }
}

extern "C" void kernel_launch(void* const* d_in, const int* in_sizes, int n_in,
                              void* d_out, int out_size, void* d_ws, size_t ws_size,
                              hipStream_t stream) {
  const float* x  = (const float*)d_in[0];
  const float* Wq = (const float*)d_in[1];
  const float* bq = (const float*)d_in[2];
  const float* Wk = (const float*)d_in[3];
  const float* bk = (const float*)d_in[4];
  const float* Wv = (const float*)d_in[5];
  const float* bv = (const float*)d_in[6];
  const float* Wo = (const float*)d_in[7];
  const float* bo = (const float*)d_in[8];
  const int*   mask = (const int*)d_in[9];
  float* out = (float*)d_out;

  char* ws = (char*)d_ws;
  int* meta  = (int*)(ws + OFF_META);
  int* ridx  = (int*)(ws + OFF_RIDX);
  f16* xb    = (f16*)(ws + OFF_XB);
  f16* wqkv  = (f16*)(ws + OFF_WQKV);
  f16* wob   = (f16*)(ws + OFF_WO);
  f16* Qh    = (f16*)(ws + OFF_Q);
  f16* Kc    = (f16*)(ws + OFF_K);
  f16* Vtc   = (f16*)(ws + OFF_VT);
  f16* PO    = (f16*)(ws + OFF_PO);

  k_prep<<<dim3(5377), 256, 0, stream>>>(x, Wq, Wk, Wv, Wo, mask, xb, ridx, meta);
  k_qkv<<<dim3(18, 32), 256, 0, stream>>>(xb, wqkv, bq, bk, bv, ridx, meta, Qh, Kc, Vtc);
  k_attn<<<dim3(768), 128, 0, stream>>>(Qh, Kc, Vtc, meta, PO);
  k_out<<<dim3(384), 256, 0, stream>>>(PO, wob, bo, out);
}